// Round 5
// baseline (180.397 us; speedup 1.0000x reference)
//
#include <hip/hip_runtime.h>
#include <cstdint>
#include <cstddef>

typedef unsigned short u16;
typedef __attribute__((ext_vector_type(8))) __bf16 bf16x8;
typedef __attribute__((ext_vector_type(8))) u16 u16x8;
typedef __attribute__((ext_vector_type(4))) float f32x4;

#define N_SEQ   2048
#define DIMC    256
#define HDIM    32
#define QSCALE  0.17677669529663687f   // 32^-0.5

__device__ __forceinline__ u16 f2bf(float f){
  union { float f; uint32_t i; } v; v.f = f;
  return (u16)((v.i + 0x7FFFu + ((v.i >> 16) & 1u)) >> 16);
}
__device__ __forceinline__ f32x4 mfma_bf16(bf16x8 a, bf16x8 b, f32x4 c){
  return __builtin_amdgcn_mfma_f32_16x16x32_bf16(a, b, c, 0, 0, 0);
}
union U8 { u16x8 u; bf16x8 b; };

// ---------------------------------------------------------------------------
// Kernel 1: W [256][768] fp32 -> Wt [768][256] bf16 (transposed)
// ---------------------------------------------------------------------------
__global__ __launch_bounds__(256) void wt_kernel(const float* __restrict__ W,
                                                 u16* __restrict__ Wt){
  __shared__ u16 T[32][33];
  int t  = threadIdx.x;
  int tx = t & 31, ty = t >> 5;
  int n0 = blockIdx.x * 32;
  int k0 = blockIdx.y * 32;
#pragma unroll
  for (int i = 0; i < 4; ++i){
    int kk = ty + i*8;
    T[kk][tx] = f2bf(W[(size_t)(k0+kk)*768 + n0 + tx]);
  }
  __syncthreads();
#pragma unroll
  for (int i = 0; i < 4; ++i){
    int nn = ty + i*8;
    Wt[(size_t)(n0+nn)*256 + k0 + tx] = T[tx][nn];
  }
}

// ---------------------------------------------------------------------------
// Kernel 2: QKV = x @ W + b.  Grid (128 m-tiles, 2 n-halves): x staged to LDS
// ONCE per block (bf16), A-frags preloaded to regs once, 6 n-subtiles looped.
// Scatter: Q[bh][n][d] (pre-scaled), K[bh][n][d], Vt[bh][d][n] (b64-packed).
// ---------------------------------------------------------------------------
__global__ __launch_bounds__(256) void qkv_kernel(const float* __restrict__ X,
                                                  const u16* __restrict__ Wt,
                                                  const float* __restrict__ bias,
                                                  u16* __restrict__ Q,
                                                  u16* __restrict__ K,
                                                  u16* __restrict__ Vt){
  __shared__ __align__(16) u16 Xs[64][264];   // row stride 528B = 33*16B
  int tid = threadIdx.x;
  int wave = tid >> 6, lane = tid & 63;
  int l16 = lane & 15, quad = lane >> 4;
  int m0 = blockIdx.x * 64;
  int nbase = blockIdx.y * 384;

  // ---- stage x tile [64][256] fp32 -> bf16 LDS, coalesced f32x4 ----
  const float* Xblk = X + (size_t)m0 * 256;
#pragma unroll
  for (int i = 0; i < 16; ++i){
    int e = i*1024 + tid*4;
    f32x4 v = *(const f32x4*)(Xblk + e);
    int row = e >> 8, col = e & 255;
    union { u16 s[4]; uint64_t q; } pk;
#pragma unroll
    for (int j = 0; j < 4; ++j) pk.s[j] = f2bf(v[j]);
    *(uint64_t*)(&Xs[row][col]) = pk.q;
  }
  __syncthreads();

  // ---- preload all 8 A-fragments for this wave's 16 rows ----
  int mrow = wave*16 + l16;
  U8 af[8];
#pragma unroll
  for (int k = 0; k < 8; ++k)
    af[k].u = *(const u16x8*)(&Xs[mrow][k*32 + quad*8]);

  // ---- 6 n-subtiles of 64 ----
  for (int j = 0; j < 6; ++j){
    int n0 = nbase + j*64;
    f32x4 acc[4] = {};
#pragma unroll
    for (int k = 0; k < 8; ++k)
#pragma unroll
      for (int s = 0; s < 4; ++s){
        U8 b; b.u = *(const u16x8*)(Wt + (size_t)(n0 + s*16 + l16)*256 + k*32 + quad*8);
        acc[s] = mfma_bf16(af[k].b, b.b, acc[s]);
      }

#pragma unroll
    for (int s = 0; s < 4; ++s){
      int c = n0 + s*16 + l16;          // output column in [0,768)
      float bv = bias[c];
      int three = c >> 8;               // 0=q 1=k 2=v (uniform per subtile)
      int h = (c >> 5) & 7;
      int d = c & 31;
      float scl = (three == 0) ? QSCALE : 1.0f;
      int mb = m0 + wave*16 + quad*4;   // first of 4 consecutive token rows
      int b_ = mb >> 11, nseq = mb & 2047;
      int bh = b_*8 + h;
      if (three == 2){
        union { u16 s4[4]; uint64_t q; } pk;
#pragma unroll
        for (int r = 0; r < 4; ++r) pk.s4[r] = f2bf(acc[s][r] + bv);
        *(uint64_t*)(&Vt[((size_t)bh*HDIM + d)*N_SEQ + nseq]) = pk.q;
      } else {
        u16* dst = (three == 0) ? Q : K;
#pragma unroll
        for (int r = 0; r < 4; ++r)
          dst[((size_t)bh*N_SEQ + nseq + r)*HDIM + d] = f2bf((acc[s][r] + bv) * scl);
      }
    }
  }
}

// ---------------------------------------------------------------------------
// Kernel 3: attention, barrier-free, no online max (scores bounded).
// Computes S^T via mfma(A=K-frag, B=Q-frag): lane l16 = query, so exp'd
// scores pack as 4 consecutive keys -> ds_write_b64; readback ds_read_b128.
// K prefetched one tile ahead; V loads issued early; only intra-wave LDS deps.
// ---------------------------------------------------------------------------
__global__ __launch_bounds__(256) void attn_kernel(const u16* __restrict__ Q,
                                                   const u16* __restrict__ Kg,
                                                   const u16* __restrict__ Vt,
                                                   float* __restrict__ out){
  __shared__ __align__(16) u16 Ps[4][16][72];  // row stride 144B = 9*16B
  int bh = blockIdx.y;
  int tid = threadIdx.x, wave = tid >> 6, lane = tid & 63;
  int l16 = lane & 15, quad = lane >> 4;
  int r0 = blockIdx.x*64 + wave*16;            // this wave's 16 q-rows

  u16 (*P)[72] = Ps[wave];

  const u16* Qb = Q  + (size_t)bh * N_SEQ * HDIM;
  const u16* Kb = Kg + (size_t)bh * N_SEQ * HDIM;
  const u16* Vb = Vt + (size_t)bh * HDIM * N_SEQ;

  U8 qt; qt.u = *(const u16x8*)(Qb + (size_t)(r0 + l16)*HDIM + quad*8);
  bf16x8 qfrag = qt.b;

  U8 onesu;
#pragma unroll
  for (int j = 0; j < 8; ++j) onesu.u[j] = 0x3F80;   // bf16 1.0
  bf16x8 ones = onesu.b;

  f32x4 O[2] = {};
  f32x4 Lacc = {};

  const int ktEnd  = (r0 < 1024) ? 16 : (r0 >> 6) + 1;
  const int maskKt = (r0 < 1024) ? -1 : (r0 >> 6);
  const int iq     = r0 + l16;     // this lane's query row (S^T: col = l16)

  // preload K fragments for kt=0
  U8 kf[4];
#pragma unroll
  for (int s = 0; s < 4; ++s)
    kf[s].u = *(const u16x8*)(Kb + (size_t)(s*16 + l16)*HDIM + quad*8);

  for (int kt = 0; kt < ktEnd; ++kt){
    int k0 = kt * 64;

    // V loads for this tile (independent -> scheduler hoists freely)
    U8 vf[2][2];
#pragma unroll
    for (int kc = 0; kc < 2; ++kc)
#pragma unroll
      for (int nd = 0; nd < 2; ++nd)
        vf[kc][nd].u = *(const u16x8*)(Vb + (size_t)(nd*16 + l16)*N_SEQ + k0 + kc*32 + quad*8);

    // S^T = K Q^T : D[key(quad*4+r)][query(l16)]
    f32x4 ST[4];
#pragma unroll
    for (int s = 0; s < 4; ++s){
      f32x4 z = {};
      ST[s] = mfma_bf16(kf[s].b, qfrag, z);
    }

    // prefetch K for next tile (clamped; wave-uniform)
    int kn = (kt + 1 < ktEnd) ? (k0 + 64) : k0;
    U8 kf2[4];
#pragma unroll
    for (int s = 0; s < 4; ++s)
      kf2[s].u = *(const u16x8*)(Kb + (size_t)(kn + s*16 + l16)*HDIM + quad*8);

    // p = exp(s) (masked -> 0); pack 4 consecutive keys -> one b64 store
    bool mask = (kt == maskKt);
#pragma unroll
    for (int s = 0; s < 4; ++s){
      int jb = k0 + s*16 + quad*4;     // first key of this 4-group
      union { u16 s4[4]; uint64_t q; } pk;
#pragma unroll
      for (int r = 0; r < 4; ++r){
        float p = __expf(ST[s][r]);
        if (mask && (jb + r > iq)) p = 0.0f;
        pk.s4[r] = f2bf(p);
      }
      *(uint64_t*)(&P[l16][s*16 + quad*4]) = pk.q;
    }

    // A-frag readback (compiler enforces LDS store->load order) + PV
#pragma unroll
    for (int kc = 0; kc < 2; ++kc){
      U8 pf; pf.u = *(const u16x8*)(&P[l16][kc*32 + quad*8]);
#pragma unroll
      for (int nd = 0; nd < 2; ++nd)
        O[nd] = mfma_bf16(pf.b, vf[kc][nd].b, O[nd]);
      Lacc = mfma_bf16(pf.b, ones, Lacc);
    }

#pragma unroll
    for (int s = 0; s < 4; ++s) kf[s] = kf2[s];
  }

  // ---- epilogue: normalize, store fp32 ----
  int b_ = bh >> 3, h = bh & 7;
#pragma unroll
  for (int r = 0; r < 4; ++r){
    float inv = 1.0f / Lacc[r];
    int i = r0 + quad*4 + r;
#pragma unroll
    for (int nd = 0; nd < 2; ++nd)
      out[((size_t)(b_*N_SEQ + i))*DIMC + h*HDIM + nd*16 + l16] = O[nd][r] * inv;
  }
}

// ---------------------------------------------------------------------------
extern "C" void kernel_launch(void* const* d_in, const int* in_sizes, int n_in,
                              void* d_out, int out_size, void* d_ws, size_t ws_size,
                              hipStream_t stream) {
  const float* x    = (const float*)d_in[0];   // [4,2048,256] fp32
  const float* W    = (const float*)d_in[1];   // [256,768]    fp32
  const float* bias = (const float*)d_in[2];   // [768]        fp32
  float* out = (float*)d_out;                  // [4,2048,256] fp32

  char* ws = (char*)d_ws;
  u16* Wt    = (u16*)(ws);                     // 393,216 B
  u16* Kbuf  = (u16*)(ws + 393216);            // 4 MB
  u16* Vtbuf = (u16*)(ws + 393216 + 4194304);  // 4 MB
  u16* Qbuf  = (u16*)(ws + 393216 + 2*4194304);// 4 MB

  wt_kernel  <<<dim3(24, 8), 256, 0, stream>>>(W, Wt);
  qkv_kernel <<<dim3(128,2), 256, 0, stream>>>(x, Wt, bias, Qbuf, Kbuf, Vtbuf);
  attn_kernel<<<dim3(32,32), 256, 0, stream>>>(Qbuf, Kbuf, Vtbuf, out);
}

// Round 6
// 164.329 us; speedup vs baseline: 1.0978x; 1.0978x over previous
//
#include <hip/hip_runtime.h>
#include <cstdint>
#include <cstddef>

typedef unsigned short u16;
typedef unsigned int u32;
typedef __attribute__((ext_vector_type(8))) __bf16 bf16x8;
typedef __attribute__((ext_vector_type(8))) u16 u16x8;
typedef __attribute__((ext_vector_type(4))) float f32x4;

#define N_SEQ   2048
#define HDIM    32
// (hd^-0.5) * log2(e): Q pre-scaled so attn uses bare v_exp_f32 (exp2)
#define QSCALE_LOG2E 0.2550540261150831f

#if __has_builtin(__builtin_amdgcn_exp2f)
#define EXP2(x) __builtin_amdgcn_exp2f(x)
#else
#define EXP2(x) exp2f(x)
#endif

__device__ __forceinline__ u16 f2bf(float f){
  union { float f; u32 i; } v; v.f = f;
  return (u16)((v.i + 0x7FFFu + ((v.i >> 16) & 1u)) >> 16);
}
__device__ __forceinline__ u32 fbits(float f){
  union { float f; u32 i; } v; v.f = f; return v.i;
}
// pack two floats -> two bf16 (round-to-nearest, ties-up) in one u32
__device__ __forceinline__ u32 pk2bf(float a, float b){
  return ((fbits(a) + 0x8000u) >> 16) | ((fbits(b) + 0x8000u) & 0xFFFF0000u);
}
__device__ __forceinline__ f32x4 mfma_bf16(bf16x8 a, bf16x8 b, f32x4 c){
  return __builtin_amdgcn_mfma_f32_16x16x32_bf16(a, b, c, 0, 0, 0);
}
union U8 { u16x8 u; bf16x8 b; };
union U2 { u32 w[2]; uint64_t q; };

// ---------------------------------------------------------------------------
// Kernel 1: W [256][768] fp32 -> Wt [768][256] bf16 (transposed)
// ---------------------------------------------------------------------------
__global__ __launch_bounds__(256) void wt_kernel(const float* __restrict__ W,
                                                 u16* __restrict__ Wt){
  __shared__ u16 T[32][33];
  int t  = threadIdx.x;
  int tx = t & 31, ty = t >> 5;
  int n0 = blockIdx.x * 32;
  int k0 = blockIdx.y * 32;
#pragma unroll
  for (int i = 0; i < 4; ++i){
    int kk = ty + i*8;
    T[kk][tx] = f2bf(W[(k0+kk)*768 + n0 + tx]);
  }
  __syncthreads();
#pragma unroll
  for (int i = 0; i < 4; ++i){
    int nn = ty + i*8;
    Wt[(n0+nn)*256 + k0 + tx] = T[tx][nn];
  }
}

// ---------------------------------------------------------------------------
// Kernel 2: QKV = x @ W + b.  Grid (128,12): 1536 blocks, 6/CU.  No LDS, no
// barrier: A-frags converted from global fp32 directly; B from L2-hot Wt.
// Scatter: Q[bh][n][d] (pre-scaled by hd^-.5*log2e), K[bh][n][d], Vt[bh][d][n].
// ---------------------------------------------------------------------------
__global__ __launch_bounds__(256) void qkv_kernel(const float* __restrict__ X,
                                                  const u16* __restrict__ Wt,
                                                  const float* __restrict__ bias,
                                                  u16* __restrict__ Q,
                                                  u16* __restrict__ K,
                                                  u16* __restrict__ Vt){
  int tid = threadIdx.x;
  int wave = tid >> 6, lane = tid & 63;
  int l16 = lane & 15, quad = lane >> 4;
  int m0 = blockIdx.x * 64 + wave * 16;   // this wave's 16 token rows
  int n0 = blockIdx.y * 64;               // 64 output cols

  // ---- A-frags: x row (m0+l16), 8 chunks of 8 floats -> bf16 ----
  const float* xr = X + (m0 + l16) * 256 + quad * 8;
  U8 af[8];
#pragma unroll
  for (int k = 0; k < 8; ++k){
    f32x4 lo = *(const f32x4*)(xr + k*32);
    f32x4 hi = *(const f32x4*)(xr + k*32 + 4);
    union { u32 w[4]; u16x8 u; } pk;
    pk.w[0] = pk2bf(lo[0], lo[1]);
    pk.w[1] = pk2bf(lo[2], lo[3]);
    pk.w[2] = pk2bf(hi[0], hi[1]);
    pk.w[3] = pk2bf(hi[2], hi[3]);
    af[k].u = pk.u;
  }

  // ---- MFMA over K=256 ----
  f32x4 acc[4] = {};
#pragma unroll
  for (int k = 0; k < 8; ++k)
#pragma unroll
    for (int s = 0; s < 4; ++s){
      U8 b; b.u = *(const u16x8*)(Wt + (n0 + s*16 + l16)*256 + k*32 + quad*8);
      acc[s] = mfma_bf16(af[k].b, b.b, acc[s]);
    }

  // ---- epilogue: bias, scale, scatter ----
#pragma unroll
  for (int s = 0; s < 4; ++s){
    int c = n0 + s*16 + l16;          // output column in [0,768)
    float bv = bias[c];
    int three = c >> 8;               // 0=q 1=k 2=v (block-uniform)
    int h = (c >> 5) & 7;
    int d = c & 31;
    float scl = (three == 0) ? QSCALE_LOG2E : 1.0f;
    int mb = m0 + quad*4;             // first of 4 consecutive token rows
    int b_ = mb >> 11, nseq = mb & 2047;
    int bh = b_*8 + h;
    if (three == 2){
      U2 pk;
      pk.w[0] = pk2bf(acc[s][0] + bv, acc[s][1] + bv);
      pk.w[1] = pk2bf(acc[s][2] + bv, acc[s][3] + bv);
      *(uint64_t*)(&Vt[(bh*HDIM + d)*N_SEQ + nseq]) = pk.q;
    } else {
      u16* dst = (three == 0) ? Q : K;
#pragma unroll
      for (int r = 0; r < 4; ++r)
        dst[(bh*N_SEQ + nseq + r)*HDIM + d] = f2bf((acc[s][r] + bv) * scl);
    }
  }
}

// ---------------------------------------------------------------------------
// Kernel 3: attention. Block = (16 q-rows, bh); 4 waves SPLIT THE KEY RANGE
// (tiles t = w, w+4, ...), partials combined in LDS (no max-rescale => sums
// just add). p = exp2(S) (Q pre-scaled by log2e). Masked diagonal tile only
// executes mask code. Grid 128x32 = 4096 blocks -> 8 blocks/CU.
// ---------------------------------------------------------------------------
__global__ __launch_bounds__(256) void attn_kernel(const u16* __restrict__ Q,
                                                   const u16* __restrict__ Kg,
                                                   const u16* __restrict__ Vt,
                                                   float* __restrict__ out){
  __shared__ __align__(16) u16  Ps[4][16][72];    // per-wave P, stride 144 B
  __shared__ __align__(8) float Obuf[4][16][34];  // partial O (even stride)
  __shared__ float Lbuf[4][16];
  int bh = blockIdx.y;
  int g  = blockIdx.x;                  // row group 0..127
  int r0 = g * 16;
  int tid = threadIdx.x, wave = tid >> 6, lane = tid & 63;
  int l16 = lane & 15, quad = lane >> 4;

  const u16* Qb = Q  + bh * (N_SEQ*HDIM);
  const u16* Kb = Kg + bh * (N_SEQ*HDIM);
  const u16* Vb = Vt + bh * (N_SEQ*HDIM);

  U8 qt; qt.u = *(const u16x8*)(Qb + (r0 + l16)*HDIM + quad*8);
  bf16x8 qfrag = qt.b;

  U8 onesu;
#pragma unroll
  for (int j = 0; j < 8; ++j) onesu.u[j] = 0x3F80;  // bf16 1.0
  bf16x8 ones = onesu.b;

  const int  T       = (r0 < 1024) ? 16 : (r0 >> 6) + 1;
  const bool hasMask = (r0 >= 1024);
  const int  iq      = r0 + l16;        // this lane's query row

  f32x4 O0 = {}, O1 = {}, L = {};
  u16 (*P)[72] = Ps[wave];

  for (int t = wave; t < T; t += 4){
    int k0 = t * 64;

    // loads for this tile (independent; scheduler pipelines them)
    U8 kf[4];
#pragma unroll
    for (int s = 0; s < 4; ++s)
      kf[s].u = *(const u16x8*)(Kb + (k0 + s*16 + l16)*HDIM + quad*8);
    U8 vf[2][2];
#pragma unroll
    for (int kc = 0; kc < 2; ++kc)
#pragma unroll
      for (int nd = 0; nd < 2; ++nd)
        vf[kc][nd].u = *(const u16x8*)(Vb + (nd*16 + l16)*N_SEQ + k0 + kc*32 + quad*8);

    // S^T: ST[s][r] = score(key = k0+s*16+quad*4+r, query = r0+l16)
    f32x4 ST[4];
#pragma unroll
    for (int s = 0; s < 4; ++s){
      f32x4 z = {};
      ST[s] = mfma_bf16(kf[s].b, qfrag, z);
    }

    // p = exp2(s); pack 4 consecutive keys -> one b64 LDS store
    if (hasMask && (t == T - 1)){
#pragma unroll
      for (int s = 0; s < 4; ++s){
        int jb = k0 + s*16 + quad*4;
        float p0 = (jb+0 > iq) ? 0.0f : EXP2(ST[s][0]);
        float p1 = (jb+1 > iq) ? 0.0f : EXP2(ST[s][1]);
        float p2 = (jb+2 > iq) ? 0.0f : EXP2(ST[s][2]);
        float p3 = (jb+3 > iq) ? 0.0f : EXP2(ST[s][3]);
        U2 pk; pk.w[0] = pk2bf(p0, p1); pk.w[1] = pk2bf(p2, p3);
        *(uint64_t*)(&P[l16][s*16 + quad*4]) = pk.q;
      }
    } else {
#pragma unroll
      for (int s = 0; s < 4; ++s){
        U2 pk;
        pk.w[0] = pk2bf(EXP2(ST[s][0]), EXP2(ST[s][1]));
        pk.w[1] = pk2bf(EXP2(ST[s][2]), EXP2(ST[s][3]));
        *(uint64_t*)(&P[l16][s*16 + quad*4]) = pk.q;
      }
    }

    // PV + denominator (ones-MFMA); LDS store->load order enforced by compiler
#pragma unroll
    for (int kc = 0; kc < 2; ++kc){
      U8 pf; pf.u = *(const u16x8*)(&P[l16][kc*32 + quad*8]);
      O0 = mfma_bf16(pf.b, vf[kc][0].b, O0);
      O1 = mfma_bf16(pf.b, vf[kc][1].b, O1);
      L  = mfma_bf16(pf.b, ones, L);
    }
  }

  // ---- in-block combine across the 4 key-splits ----
#pragma unroll
  for (int r = 0; r < 4; ++r){
    Obuf[wave][quad*4 + r][l16]      = O0[r];
    Obuf[wave][quad*4 + r][16 + l16] = O1[r];
  }
  if (l16 == 0){
#pragma unroll
    for (int r = 0; r < 4; ++r) Lbuf[wave][quad*4 + r] = L[r];
  }
  __syncthreads();

  int row = tid >> 4;              // 0..15
  int c2  = (tid & 15) * 2;        // even col in [0,32)
  float a = 0.f, b2 = 0.f, Ls = 0.f;
#pragma unroll
  for (int w = 0; w < 4; ++w){
    a  += Obuf[w][row][c2];
    b2 += Obuf[w][row][c2 + 1];
    Ls += Lbuf[w][row];
  }
  float inv = 1.0f / Ls;
  int b_ = bh >> 3, h = bh & 7;
  float2 st; st.x = a * inv; st.y = b2 * inv;
  *(float2*)(&out[(b_*N_SEQ + r0 + row)*256 + h*32 + c2]) = st;
}

// ---------------------------------------------------------------------------
extern "C" void kernel_launch(void* const* d_in, const int* in_sizes, int n_in,
                              void* d_out, int out_size, void* d_ws, size_t ws_size,
                              hipStream_t stream) {
  const float* x    = (const float*)d_in[0];   // [4,2048,256] fp32
  const float* W    = (const float*)d_in[1];   // [256,768]    fp32
  const float* bias = (const float*)d_in[2];   // [768]        fp32
  float* out = (float*)d_out;                  // [4,2048,256] fp32

  char* ws = (char*)d_ws;
  u16* Wt    = (u16*)(ws);                     // 393,216 B
  u16* Kbuf  = (u16*)(ws + 393216);            // 4 MB
  u16* Vtbuf = (u16*)(ws + 393216 + 4194304);  // 4 MB
  u16* Qbuf  = (u16*)(ws + 393216 + 2*4194304);// 4 MB

  wt_kernel  <<<dim3(24, 8),  256, 0, stream>>>(W, Wt);
  qkv_kernel <<<dim3(128,12), 256, 0, stream>>>(x, Wt, bias, Qbuf, Kbuf, Vtbuf);
  attn_kernel<<<dim3(128,32), 256, 0, stream>>>(Qbuf, Kbuf, Vtbuf, out);
}

// Round 7
// 158.735 us; speedup vs baseline: 1.1365x; 1.0352x over previous
//
#include <hip/hip_runtime.h>
#include <cstdint>
#include <cstddef>

typedef unsigned short u16;
typedef unsigned int u32;
typedef __attribute__((ext_vector_type(8))) __bf16 bf16x8;
typedef __attribute__((ext_vector_type(8))) u16 u16x8;
typedef __attribute__((ext_vector_type(4))) float f32x4;

#define N_SEQ   2048
#define HDIM    32
// (hd^-0.5) * log2(e): Q pre-scaled so attn uses bare exp2
#define QSCALE_LOG2E 0.2550540261150831f

#if __has_builtin(__builtin_amdgcn_exp2f)
#define EXP2(x) __builtin_amdgcn_exp2f(x)
#else
#define EXP2(x) exp2f(x)
#endif

__device__ __forceinline__ u16 f2bf(float f){
  union { float f; u32 i; } v; v.f = f;
  return (u16)((v.i + 0x7FFFu + ((v.i >> 16) & 1u)) >> 16);
}
__device__ __forceinline__ u32 fbits(float f){
  union { float f; u32 i; } v; v.f = f; return v.i;
}
__device__ __forceinline__ u32 pk2bf(float a, float b){
  return ((fbits(a) + 0x8000u) >> 16) | ((fbits(b) + 0x8000u) & 0xFFFF0000u);
}
__device__ __forceinline__ f32x4 mfma_bf16(bf16x8 a, bf16x8 b, f32x4 c){
  return __builtin_amdgcn_mfma_f32_16x16x32_bf16(a, b, c, 0, 0, 0);
}
union U8 { u16x8 u; bf16x8 b; };
union U2 { u32 w[2]; uint64_t q; };

// ---------------------------------------------------------------------------
// Kernel 1: W [256][768] fp32 -> Wt [768][256] bf16 (transposed)
// ---------------------------------------------------------------------------
__global__ __launch_bounds__(256) void wt_kernel(const float* __restrict__ W,
                                                 u16* __restrict__ Wt){
  __shared__ u16 T[32][33];
  int t  = threadIdx.x;
  int tx = t & 31, ty = t >> 5;
  int n0 = blockIdx.x * 32;
  int k0 = blockIdx.y * 32;
#pragma unroll
  for (int i = 0; i < 4; ++i){
    int kk = ty + i*8;
    T[kk][tx] = f2bf(W[(k0+kk)*768 + n0 + tx]);
  }
  __syncthreads();
#pragma unroll
  for (int i = 0; i < 4; ++i){
    int nn = ty + i*8;
    Wt[(n0+nn)*256 + k0 + tx] = T[tx][nn];
  }
}

// ---------------------------------------------------------------------------
// Kernel 2: QKV = x @ W + b.  Grid (128,12).  Register A-frags from global x.
// Q/K scatter as before; V goes through LDS so global stores are per-d
// 64-token contiguous 128B bursts (2 CLs/inst instead of 64).
// ---------------------------------------------------------------------------
__global__ __launch_bounds__(256) void qkv_kernel(const float* __restrict__ X,
                                                  const u16* __restrict__ Wt,
                                                  const float* __restrict__ bias,
                                                  u16* __restrict__ Q,
                                                  u16* __restrict__ K,
                                                  u16* __restrict__ Vt){
  __shared__ u16 Vs[64][66];              // [c_local][token], +2 pad
  int tid = threadIdx.x;
  int wave = tid >> 6, lane = tid & 63;
  int l16 = lane & 15, quad = lane >> 4;
  int m0 = blockIdx.x * 64;
  int mw = m0 + wave * 16;                // this wave's 16 token rows
  int n0 = blockIdx.y * 64;               // 64 output cols (uniform q/k/v)
  const int three = n0 >> 8;              // 0=q 1=k 2=v (block-uniform)

  // ---- A-frags: x row (mw+l16), 8 chunks of 8 floats -> bf16 ----
  const float* xr = X + (mw + l16) * 256 + quad * 8;
  U8 af[8];
#pragma unroll
  for (int k = 0; k < 8; ++k){
    f32x4 lo = *(const f32x4*)(xr + k*32);
    f32x4 hi = *(const f32x4*)(xr + k*32 + 4);
    union { u32 w[4]; u16x8 u; } pk;
    pk.w[0] = pk2bf(lo[0], lo[1]);
    pk.w[1] = pk2bf(lo[2], lo[3]);
    pk.w[2] = pk2bf(hi[0], hi[1]);
    pk.w[3] = pk2bf(hi[2], hi[3]);
    af[k].u = pk.u;
  }

  // ---- MFMA over K=256 ----
  f32x4 acc[4] = {};
#pragma unroll
  for (int k = 0; k < 8; ++k)
#pragma unroll
    for (int s = 0; s < 4; ++s){
      U8 b; b.u = *(const u16x8*)(Wt + (n0 + s*16 + l16)*256 + k*32 + quad*8);
      acc[s] = mfma_bf16(af[k].b, b.b, acc[s]);
    }

  // ---- epilogue ----
  int b_ = m0 >> 11, nseq0 = m0 & 2047;   // block rows all in one batch
#pragma unroll
  for (int s = 0; s < 4; ++s){
    int cl = s*16 + l16;                  // col within block [0,64)
    int c = n0 + cl;
    float bv = bias[c];
    int h = (c >> 5) & 7;
    int d = c & 31;
    int tok = wave*16 + quad*4;           // first of 4 consecutive tokens
    if (three == 2){
      U2 pk;
      pk.w[0] = pk2bf(acc[s][0] + bv, acc[s][1] + bv);
      pk.w[1] = pk2bf(acc[s][2] + bv, acc[s][3] + bv);
      *(uint64_t*)(&Vs[cl][tok]) = pk.q;
    } else {
      float scl = (three == 0) ? QSCALE_LOG2E : 1.0f;
      u16* dst = (three == 0) ? Q : K;
      int bh = b_*8 + h;
#pragma unroll
      for (int r = 0; r < 4; ++r)
        dst[(bh*N_SEQ + nseq0 + tok + r)*HDIM + d] = f2bf((acc[s][r] + bv) * scl);
    }
  }

  if (three == 2){
    __syncthreads();
    // wave w writes c_locals w*16..w*16+15; lanes = 64 consecutive tokens
#pragma unroll
    for (int i = 0; i < 16; ++i){
      int cl = wave*16 + i;
      int c = n0 + cl;
      int h = (c >> 5) & 7, d = c & 31;
      int bh = b_*8 + h;
      Vt[(bh*HDIM + d)*N_SEQ + nseq0 + lane] = Vs[cl][lane];
    }
  }
}

// ---------------------------------------------------------------------------
// Kernel 3: attention. Block = 4 perfectly-balanced items {2j,2j+1,64+j,127-j}
// (cost = 81 key-tiles for EVERY block). Per item: 4 waves k-split (stride 4).
// Software pipeline: K prefetched 1 tile ahead, P double-buffered in LDS,
// V loaded 1 tile late -> PV(t-1) overlaps exp/store(t). Grid 32x32 = 1024
// blocks, all co-resident at 4/CU. p = exp2(S) (Q pre-scaled by log2e).
// ---------------------------------------------------------------------------
__global__ __launch_bounds__(256) void attn_kernel(const u16* __restrict__ Q,
                                                   const u16* __restrict__ Kg,
                                                   const u16* __restrict__ Vt,
                                                   float* __restrict__ out){
  __shared__ __align__(16) u16  Ps[4][2][16][72];   // per-wave dbuf P
  __shared__ __align__(8) float Obuf[4][16][34];
  __shared__ float Lbuf[4][16];
  int j  = blockIdx.x;                   // 0..31
  int bh = blockIdx.y;
  int tid = threadIdx.x, wave = tid >> 6, lane = tid & 63;
  int l16 = lane & 15, quad = lane >> 4;

  const u16* Qb = Q  + bh * (N_SEQ*HDIM);
  const u16* Kb = Kg + bh * (N_SEQ*HDIM);
  const u16* Vb = Vt + bh * (N_SEQ*HDIM);

  U8 onesu;
#pragma unroll
  for (int q = 0; q < 8; ++q) onesu.u[q] = 0x3F80;  // bf16 1.0
  bf16x8 ones = onesu.b;

  int glist[4] = { 2*j, 2*j + 1, 64 + j, 127 - j };

  for (int it = 0; it < 4; ++it){
    int g  = glist[it];
    int r0 = g * 16;
    const int  T       = (r0 < 1024) ? 16 : (r0 >> 6) + 1;
    const bool hasMask = (r0 >= 1024);
    const int  iq      = r0 + l16;

    U8 qt; qt.u = *(const u16x8*)(Qb + (r0 + l16)*HDIM + quad*8);
    bf16x8 qfrag = qt.b;

    f32x4 O0 = {}, O1 = {}, L = {};
    int sbuf = 0, tprev = -1;

    // preload K for first tile
    U8 kfA[4], kfB[4], vf[2][2];
#pragma unroll
    for (int s = 0; s < 4; ++s)
      kfA[s].u = *(const u16x8*)(Kb + (wave*64 + s*16 + l16)*HDIM + quad*8);

    for (int t = wave; t < T; t += 4){
      int k0 = t * 64;
      // prefetch K(t+4) (clamped)
      int kn = (t + 4 < T) ? (k0 + 256) : k0;
#pragma unroll
      for (int s = 0; s < 4; ++s)
        kfB[s].u = *(const u16x8*)(Kb + (kn + s*16 + l16)*HDIM + quad*8);
      // V for previous tile (consumed at end of this iteration)
      if (tprev >= 0){
#pragma unroll
        for (int kc = 0; kc < 2; ++kc)
#pragma unroll
          for (int nd = 0; nd < 2; ++nd)
            vf[kc][nd].u = *(const u16x8*)(Vb + (nd*16 + l16)*N_SEQ + tprev*64 + kc*32 + quad*8);
      }

      // S^T = K Q^T
      f32x4 ST[4];
#pragma unroll
      for (int s = 0; s < 4; ++s){
        f32x4 z = {};
        ST[s] = mfma_bf16(kfA[s].b, qfrag, z);
      }

      // p = exp2(s) -> P buffer sbuf
      u16 (*Pw)[72] = Ps[wave][sbuf];
      if (hasMask && (t == T - 1)){
#pragma unroll
        for (int s = 0; s < 4; ++s){
          int jb = k0 + s*16 + quad*4;
          float p0 = (jb+0 > iq) ? 0.0f : EXP2(ST[s][0]);
          float p1 = (jb+1 > iq) ? 0.0f : EXP2(ST[s][1]);
          float p2 = (jb+2 > iq) ? 0.0f : EXP2(ST[s][2]);
          float p3 = (jb+3 > iq) ? 0.0f : EXP2(ST[s][3]);
          U2 pk; pk.w[0] = pk2bf(p0, p1); pk.w[1] = pk2bf(p2, p3);
          *(uint64_t*)(&Pw[l16][s*16 + quad*4]) = pk.q;
        }
      } else {
#pragma unroll
        for (int s = 0; s < 4; ++s){
          U2 pk;
          pk.w[0] = pk2bf(EXP2(ST[s][0]), EXP2(ST[s][1]));
          pk.w[1] = pk2bf(EXP2(ST[s][2]), EXP2(ST[s][3]));
          *(uint64_t*)(&Pw[l16][s*16 + quad*4]) = pk.q;
        }
      }

      // PV for previous tile from the other buffer
      if (tprev >= 0){
        u16 (*Pr)[72] = Ps[wave][sbuf ^ 1];
#pragma unroll
        for (int kc = 0; kc < 2; ++kc){
          U8 pf; pf.u = *(const u16x8*)(&Pr[l16][kc*32 + quad*8]);
          O0 = mfma_bf16(pf.b, vf[kc][0].b, O0);
          O1 = mfma_bf16(pf.b, vf[kc][1].b, O1);
          L  = mfma_bf16(pf.b, ones, L);
        }
      }

#pragma unroll
      for (int s = 0; s < 4; ++s) kfA[s] = kfB[s];
      tprev = t; sbuf ^= 1;
    }

    // tail: PV for the last tile
    {
#pragma unroll
      for (int kc = 0; kc < 2; ++kc)
#pragma unroll
        for (int nd = 0; nd < 2; ++nd)
          vf[kc][nd].u = *(const u16x8*)(Vb + (nd*16 + l16)*N_SEQ + tprev*64 + kc*32 + quad*8);
      u16 (*Pr)[72] = Ps[wave][sbuf ^ 1];
#pragma unroll
      for (int kc = 0; kc < 2; ++kc){
        U8 pf; pf.u = *(const u16x8*)(&Pr[l16][kc*32 + quad*8]);
        O0 = mfma_bf16(pf.b, vf[kc][0].b, O0);
        O1 = mfma_bf16(pf.b, vf[kc][1].b, O1);
        L  = mfma_bf16(pf.b, ones, L);
      }
    }

    // ---- combine the 4 key-splits, store ----
#pragma unroll
    for (int r = 0; r < 4; ++r){
      Obuf[wave][quad*4 + r][l16]      = O0[r];
      Obuf[wave][quad*4 + r][16 + l16] = O1[r];
    }
    if (l16 == 0){
#pragma unroll
      for (int r = 0; r < 4; ++r) Lbuf[wave][quad*4 + r] = L[r];
    }
    __syncthreads();

    {
      int row = tid >> 4;              // 0..15
      int c2  = (tid & 15) * 2;        // even col in [0,32)
      float a = 0.f, b2 = 0.f, Ls = 0.f;
#pragma unroll
      for (int w = 0; w < 4; ++w){
        a  += Obuf[w][row][c2];
        b2 += Obuf[w][row][c2 + 1];
        Ls += Lbuf[w][row];
      }
      float inv = 1.0f / Ls;
      int b_ = bh >> 3, h = bh & 7;
      float2 st; st.x = a * inv; st.y = b2 * inv;
      *(float2*)(&out[(b_*N_SEQ + r0 + row)*256 + h*32 + c2]) = st;
    }
    __syncthreads();   // Obuf/Lbuf reuse by next item
  }
}

// ---------------------------------------------------------------------------
extern "C" void kernel_launch(void* const* d_in, const int* in_sizes, int n_in,
                              void* d_out, int out_size, void* d_ws, size_t ws_size,
                              hipStream_t stream) {
  const float* x    = (const float*)d_in[0];   // [4,2048,256] fp32
  const float* W    = (const float*)d_in[1];   // [256,768]    fp32
  const float* bias = (const float*)d_in[2];   // [768]        fp32
  float* out = (float*)d_out;                  // [4,2048,256] fp32

  char* ws = (char*)d_ws;
  u16* Wt    = (u16*)(ws);                     // 393,216 B
  u16* Kbuf  = (u16*)(ws + 393216);            // 4 MB
  u16* Vtbuf = (u16*)(ws + 393216 + 4194304);  // 4 MB
  u16* Qbuf  = (u16*)(ws + 393216 + 2*4194304);// 4 MB

  wt_kernel  <<<dim3(24, 8),  256, 0, stream>>>(W, Wt);
  qkv_kernel <<<dim3(128,12), 256, 0, stream>>>(x, Wt, bias, Qbuf, Kbuf, Vtbuf);
  attn_kernel<<<dim3(32, 32), 256, 0, stream>>>(Qbuf, Kbuf, Vtbuf, out);
}